// Round 5
// baseline (317.686 us; speedup 1.0000x reference)
//
#include <hip/hip_runtime.h>
#include <hip/hip_cooperative_groups.h>
#include <math.h>

namespace cg = cooperative_groups;

// Problem constants
constexpr int NH    = 778;           // hand verts per batch
constexpr int GRIDC = 16;            // cells per axis (0.1 m cube -> 6.25 mm cells)
constexpr int NCELL = GRIDC * GRIDC * GRIDC;   // 4096
constexpr int CAP   = 40;            // bucket cap (Poisson mean ~9.8; P(>40)~1e-14)
constexpr float CELL     = 0.1f / GRIDC;       // 0.00625
constexpr float INV_CELL = GRIDC / 0.1f;       // 160
constexpr int NXCD = 8;              // MI355X XCD count
constexpr int NSH  = 64;             // stat shards, one 64B line each
constexpr int SPEC = 8;              // speculative bucket entries per lane (covers n<=16)

// R16 = R15 with the compile fix (hipDeviceAttributeMultiprocessorCount —
// lowercase 'p' in HIP, unlike CUDA) + hipError_t casts.
// R15: (a) cooperative mega-kernel — zero+bin+query+finalize in ONE dispatch
// with grid.sync() phase barriers (removes 4 dispatch boundaries + memset
// kernel; grid sized by occupancy API, multi-dispatch fallback kept);
// (b) query speculation — bucket entry addresses don't depend on cnt, so
// load 8 entries/lane unconditionally IN PARALLEL with the cnt load: one L2
// round-trip per cell instead of 1 + n/2 dependent rounds (~98% of cells).

struct alignas(64) Shard {
    double sd, sp, sa;   // sum_d, pen_sum, att_sum
    int cp, ca;          // pen_cnt, att_cnt
    int pad[3];
};

__device__ __forceinline__ int clampc(int v) {
    return min(GRIDC - 1, max(0, v));
}

// ---------------------------------------------------------------------------
// Shared device body: bin 4 points (one thread's slice) into buckets.
// ---------------------------------------------------------------------------
__device__ __forceinline__ void bin4(
    const float* __restrict__ obj, int* __restrict__ cnt, int* __restrict__ ocnt,
    float4* __restrict__ buckets, float4* __restrict__ ovf,
    int b, int V, int p0)
{
    float px[4], py[4], pz[4];
    int np;
    const size_t fbase = ((size_t)b * V + p0) * 3;
    if (p0 + 4 <= V && (fbase & 3) == 0) {
        const float4* src = (const float4*)(obj + fbase);
        const float4 A = src[0], Bv = src[1], C = src[2];
        px[0]=A.x;  py[0]=A.y;  pz[0]=A.z;
        px[1]=A.w;  py[1]=Bv.x; pz[1]=Bv.y;
        px[2]=Bv.z; py[2]=Bv.w; pz[2]=C.x;
        px[3]=C.y;  py[3]=C.z;  pz[3]=C.w;
        np = 4;
    } else {
        np = min(4, V - p0);
        for (int q = 0; q < np; ++q) {
            px[q] = obj[fbase + 3 * q + 0];
            py[q] = obj[fbase + 3 * q + 1];
            pz[q] = obj[fbase + 3 * q + 2];
        }
    }
    const int cb = b * NCELL;
#pragma unroll
    for (int q = 0; q < 4; ++q) {
        if (q >= np) break;
        const int cx = clampc((int)(px[q] * INV_CELL));
        const int cy = clampc((int)(py[q] * INV_CELL));
        const int cz = clampc((int)(pz[q] * INV_CELL));
        const int cell = cb + (cz * GRIDC + cy) * GRIDC + cx;
        const int idx = atomicAdd(&cnt[cell], 1);
        if (idx < CAP) {
            buckets[(size_t)cell * CAP + idx] = make_float4(px[q], py[q], pz[q], 0.f);
        } else {
            const int oi = atomicAdd(ocnt, 1);   // oi < total always
            ovf[oi] = make_float4(px[q], py[q], pz[q], __int_as_float(b));
        }
    }
}

// ---------------------------------------------------------------------------
// Shared device body: exact grid NN for one query, one wave. Returns best d2
// in ALL lanes. Exactness: h lies inside its own cell, so after completing
// cube radius r-1 every unscanned point is >= (r-1)*CELL away; stop iff
// best <= ((r-1)*CELL)^2.  Speculative flat loads: bp[sub+2j] addresses are
// independent of n -> issue with the cnt load, one L2 round per cell.
// ---------------------------------------------------------------------------
__device__ float query_one(
    const float* __restrict__ hand, const int* __restrict__ cnt,
    const float4* __restrict__ buckets, const float4* __restrict__ ovf,
    int on, int b, int i, int lane)
{
    const float hx = hand[3 * i + 0];
    const float hy = hand[3 * i + 1];
    const float hz = hand[3 * i + 2];
    const int hcx = clampc((int)(hx * INV_CELL));
    const int hcy = clampc((int)(hy * INV_CELL));
    const int hcz = clampc((int)(hz * INV_CELL));
    const int cbase = b * NCELL;

    float best = 3.4e38f;

    // phase 1: radius-1 cube (27 cells), 2 lanes per cell (lanes 0..53)
    if (lane < 54) {
        const int cl  = lane >> 1;
        const int sub = lane & 1;
        const int cx = hcx + (cl % 3) - 1;
        const int cy = hcy + ((cl / 3) % 3) - 1;
        const int cz = hcz + (cl / 9) - 1;
        if (cx >= 0 && cx < GRIDC && cy >= 0 && cy < GRIDC &&
            cz >= 0 && cz < GRIDC) {
            const int cell = cbase + (cz * GRIDC + cy) * GRIDC + cx;
            const float4* bp = buckets + (size_t)cell * CAP;
            const int n = min(cnt[cell], CAP);     // load (parallel with below)
            float4 e[SPEC];
#pragma unroll
            for (int j = 0; j < SPEC; ++j) e[j] = bp[sub + 2 * j];  // speculative
#pragma unroll
            for (int j = 0; j < SPEC; ++j) {
                if (sub + 2 * j < n) {
                    const float dx = e[j].x - hx, dy = e[j].y - hy, dz = e[j].z - hz;
                    best = fminf(best, fmaf(dx, dx, fmaf(dy, dy, dz * dz)));
                }
            }
            for (int k = sub + 2 * SPEC; k < n; k += 2) {   // rare tail (n>16)
                const float4 p = bp[k];
                const float dx = p.x - hx, dy = p.y - hy, dz = p.z - hz;
                best = fminf(best, fmaf(dx, dx, fmaf(dy, dy, dz * dz)));
            }
        }
    }

    // overflow list (normally empty), lane-strided
    for (int k = lane; k < on; k += 64) {
        const float4 p = ovf[k];
        if (__float_as_int(p.w) == b) {
            const float dx = p.x - hx, dy = p.y - hy, dz = p.z - hz;
            best = fminf(best, fmaf(dx, dx, fmaf(dy, dy, dz * dz)));
        }
    }

#pragma unroll
    for (int d = 1; d < 64; d <<= 1) best = fminf(best, __shfl_xor(best, d));

    // rare path: expanding shells, lane-strided over shell cells
    for (int r = 2; r < GRIDC; ++r) {
        const float bnd = (float)(r - 1) * CELL;
        if (best <= bnd * bnd) break;
        const int side = 2 * r + 1;
        const int ncells = side * side * side;
        for (int ci = lane; ci < ncells; ci += 64) {
            const int dx = ci % side - r;
            const int dy = (ci / side) % side - r;
            const int dz = ci / (side * side) - r;
            if (max(max(abs(dx), abs(dy)), abs(dz)) != r) continue; // shell only
            const int cx = hcx + dx, cy = hcy + dy, cz = hcz + dz;
            if (cx < 0 || cx >= GRIDC || cy < 0 || cy >= GRIDC ||
                cz < 0 || cz >= GRIDC) continue;
            const int cell = cbase + (cz * GRIDC + cy) * GRIDC + cx;
            const int n = min(cnt[cell], CAP);
            const float4* bp = buckets + (size_t)cell * CAP;
            for (int k = 0; k < n; ++k) {
                const float4 p = bp[k];
                const float ddx = p.x - hx, ddy = p.y - hy, ddz = p.z - hz;
                best = fminf(best, fmaf(ddx, ddx, fmaf(ddy, ddy, ddz * ddz)));
            }
        }
#pragma unroll
        for (int d = 1; d < 64; d <<= 1) best = fminf(best, __shfl_xor(best, d));
    }
    return best;
}

// ---------------------------------------------------------------------------
// Stat helper: lane-0 accumulation for one finished query.
// ---------------------------------------------------------------------------
__device__ __forceinline__ void accum_stats(
    float best, int ql, double& sd, double& sp, double& sa, int& cp, int& ca)
{
    constexpr float COLL = 0.005f;
    constexpr float CONT = 0.01f;
    const float d = sqrtf(fmaxf(best, 0.f));
    sd += (double)d;
    if (d < COLL) { const float t = COLL - d; sp += (double)(t * t); cp++; }
    const bool isc = (ql == 745) | (ql == 317) | (ql == 444) | (ql == 556) |
                     (ql == 673) | (ql == 95)  | (ql == 182) | (ql == 234) |
                     (ql == 279) | (ql == 320);
    if (isc & (d > COLL) & (d < CONT)) { sa += (double)(d * d); ca++; }
}

// ---------------------------------------------------------------------------
// R15 cooperative mega-kernel: zero -> bin -> query(+stats) -> finalize, one
// dispatch. All blocks execute all phases (guards inside, NO early returns —
// every block must reach every grid.sync()). Batch affinity: b = bid % B
// (B==8 -> bid%8 == XCD id, same mapping as R13/R14).
// ---------------------------------------------------------------------------
__global__ __launch_bounds__(256, 4) void mega_kernel(
    const float* __restrict__ hand, const float* __restrict__ obj,
    int* __restrict__ cnt, int* __restrict__ ocnt,
    float4* __restrict__ buckets, float4* __restrict__ ovf,
    Shard* __restrict__ shards, float* __restrict__ out,
    int B, int V)
{
    cg::grid_group grid = cg::this_grid();
    const int tid  = threadIdx.x;
    const int wave = tid >> 6;
    const int lane = tid & 63;
    const int nblk = (int)gridDim.x;          // multiple of B (launcher-enforced)
    const int gtid = (int)blockIdx.x * 256 + tid;
    const int gthreads = nblk * 256;

    // ---- phase 0: zero cnt + shards + ocnt (workspace is re-poisoned) ----
    const int ztot = B * NCELL;
    for (int i = gtid; i < ztot; i += gthreads) cnt[i] = 0;
    if (gtid < NSH) {
        shards[gtid].sd = 0.0; shards[gtid].sp = 0.0; shards[gtid].sa = 0.0;
        shards[gtid].cp = 0;   shards[gtid].ca = 0;
    }
    if (gtid == 0) *ocnt = 0;
    grid.sync();

    // ---- phase 1: bin (4 points/thread granularity) ----
    const int b    = (int)blockIdx.x % B;     // batch affinity
    const int rank = (int)blockIdx.x / B;
    const int bpg  = nblk / B;                // blocks per batch group
    const int bt   = rank * 256 + tid;        // thread index within batch group
    const int bthreads = bpg * 256;
    for (int p0 = bt * 4; p0 < V; p0 += bthreads * 4)
        bin4(obj, cnt, ocnt, buckets, ovf, b, V, p0);
    grid.sync();

    // ---- phase 2: query, one wave per query, grid-stride within batch ----
    const int on = *ocnt;
    const int bwid = rank * 4 + wave;         // wave id within batch group
    const int bwaves = bpg * 4;
    double asd = 0.0, asp = 0.0, asa = 0.0;
    int acp = 0, aca = 0;
    for (int ql = bwid; ql < NH; ql += bwaves) {
        const float best = query_one(hand, cnt, buckets, ovf, on,
                                     b, b * NH + ql, lane);
        if (lane == 0) accum_stats(best, ql, asd, asp, asa, acp, aca);
    }
    // block-level stat reduction + one set of relaxed shard atomics
    __shared__ double ssd[4], ssp[4], ssa[4];
    __shared__ int scp[4], sca[4];
    if (lane == 0) { ssd[wave]=asd; ssp[wave]=asp; ssa[wave]=asa;
                     scp[wave]=acp; sca[wave]=aca; }
    __syncthreads();
    if (tid == 0) {
        Shard* s = &shards[blockIdx.x & (NSH - 1)];
        atomicAdd(&s->sd, ssd[0]+ssd[1]+ssd[2]+ssd[3]);
        atomicAdd(&s->sp, ssp[0]+ssp[1]+ssp[2]+ssp[3]);
        atomicAdd(&s->sa, ssa[0]+ssa[1]+ssa[2]+ssa[3]);
        atomicAdd(&s->cp, scp[0]+scp[1]+scp[2]+scp[3]);
        atomicAdd(&s->ca, sca[0]+sca[1]+sca[2]+sca[3]);
    }
    grid.sync();

    // ---- phase 3: one wave reduces the 64 shards -> 6 outputs ----
    if (blockIdx.x == 0 && tid < 64) {
        const int l = tid;
        double sd = shards[l].sd, sp = shards[l].sp, sa = shards[l].sa;
        int cp = shards[l].cp, ca = shards[l].ca;
#pragma unroll
        for (int d = 1; d < 64; d <<= 1) {
            sd += __shfl_xor(sd, d); sp += __shfl_xor(sp, d);
            sa += __shfl_xor(sa, d);
            cp += __shfl_xor(cp, d); ca += __shfl_xor(ca, d);
        }
        if (l == 0) {
            const double pen_loss = cp > 0 ? sp / (double)cp : 0.0;
            const double att_loss = ca > 0 ? sa / (double)ca : 0.0;
            out[0] = (float)(100.0 * pen_loss + 10.0 * att_loss);
            out[1] = (float)pen_loss;
            out[2] = (float)att_loss;
            out[3] = (float)(sd / (double)(B * NH));
            out[4] = (float)ca;
            out[5] = (float)cp;
        }
    }
}

// ---------------------------------------------------------------------------
// Multi-dispatch fallback path (R14 kernels) if cooperative launch is
// unavailable. Same device bodies.
// ---------------------------------------------------------------------------
__global__ __launch_bounds__(256) void bin_kernel(
    const float* __restrict__ obj, int* __restrict__ cnt, int* __restrict__ ocnt,
    float4* __restrict__ buckets, float4* __restrict__ ovf,
    int B, int V, int bpb)
{
    const int w = (blockIdx.x % NXCD) * (gridDim.x / NXCD) + blockIdx.x / NXCD;
    const int b = w / bpb;
    if (b >= B) return;
    const int p0 = ((w % bpb) * 256 + (int)threadIdx.x) * 4;
    if (p0 >= V) return;
    bin4(obj, cnt, ocnt, buckets, ovf, b, V, p0);
}

__global__ __launch_bounds__(256) void query_kernel(
    const float* __restrict__ hand, const int* __restrict__ cnt,
    const float4* __restrict__ buckets, const float4* __restrict__ ovf,
    const int* __restrict__ ocnt, Shard* __restrict__ shards,
    int B, int bpq)
{
    const int tid  = threadIdx.x;
    const int wave = tid >> 6;
    const int lane = tid & 63;
    const int w  = (blockIdx.x % NXCD) * (gridDim.x / NXCD) + blockIdx.x / NXCD;
    const int b  = w / bpq;
    const int ql = (w % bpq) * 4 + wave;
    const bool valid = (b < B) && (ql < NH);

    double sd = 0.0, sp = 0.0, sa = 0.0;
    int cp = 0, ca = 0;
    if (valid) {
        const float best = query_one(hand, cnt, buckets, ovf, *ocnt,
                                     b, b * NH + ql, lane);
        if (lane == 0) accum_stats(best, ql, sd, sp, sa, cp, ca);
    }
    __shared__ double ssd[4], ssp[4], ssa[4];
    __shared__ int scp[4], sca[4];
    if (lane == 0) { ssd[wave]=sd; ssp[wave]=sp; ssa[wave]=sa;
                     scp[wave]=cp; sca[wave]=ca; }
    __syncthreads();
    if (tid == 0) {
        Shard* s = &shards[blockIdx.x & (NSH - 1)];
        atomicAdd(&s->sd, ssd[0]+ssd[1]+ssd[2]+ssd[3]);
        atomicAdd(&s->sp, ssp[0]+ssp[1]+ssp[2]+ssp[3]);
        atomicAdd(&s->sa, ssa[0]+ssa[1]+ssa[2]+ssa[3]);
        atomicAdd(&s->cp, scp[0]+scp[1]+scp[2]+scp[3]);
        atomicAdd(&s->ca, sca[0]+sca[1]+sca[2]+sca[3]);
    }
}

__global__ __launch_bounds__(64) void finalize_tiny(
    const Shard* __restrict__ shards, float* __restrict__ out, int nq)
{
    const int l = threadIdx.x;
    double sd = shards[l].sd, sp = shards[l].sp, sa = shards[l].sa;
    int cp = shards[l].cp, ca = shards[l].ca;
#pragma unroll
    for (int d = 1; d < 64; d <<= 1) {
        sd += __shfl_xor(sd, d); sp += __shfl_xor(sp, d);
        sa += __shfl_xor(sa, d);
        cp += __shfl_xor(cp, d); ca += __shfl_xor(ca, d);
    }
    if (l == 0) {
        const double pen_loss = cp > 0 ? sp / (double)cp : 0.0;
        const double att_loss = ca > 0 ? sa / (double)ca : 0.0;
        out[0] = (float)(100.0 * pen_loss + 10.0 * att_loss);
        out[1] = (float)pen_loss;
        out[2] = (float)att_loss;
        out[3] = (float)(sd / (double)nq);
        out[4] = (float)ca;
        out[5] = (float)cp;
    }
}

// ---------------------------------------------------------------------------
// Brute-force fallback (ws too small for grid). Unchanged from R10/R14.
// ---------------------------------------------------------------------------
typedef float v2f __attribute__((ext_vector_type(2)));
constexpr int FT = 16, FG = 4, FBLK = 256, FCHUNK = 2560;
constexpr int FNBX = (NH + FG * FT - 1) / (FG * FT);
constexpr int FLPP = FCHUNK / FBLK, FPP = FLPP / 2;

__global__ __launch_bounds__(FBLK, 2) void nn_brute_kernel(
    const float* __restrict__ hand, const float* __restrict__ obj,
    unsigned int* __restrict__ minb, int V)
{
    __shared__ float s_red[4][16 * 65];
    const int bx = blockIdx.x, c = blockIdx.y, b = blockIdx.z;
    const int tid = threadIdx.x, wave = tid >> 6, lane = tid & 63;
    const int r = lane & 15, seg = lane >> 4;
    const float* ob = obj + (size_t)b * V * 3;
    const int base = c * FCHUNK + tid;
    v2f ox2[FPP], oy2[FPP], oz2[FPP], oq2[FPP];
#pragma unroll
    for (int p = 0; p < FPP; ++p) {
        const int ja = min(base + (2 * p + 0) * FBLK, V - 1);
        const int jb = min(base + (2 * p + 1) * FBLK, V - 1);
        const float xa = ob[3 * ja], ya = ob[3 * ja + 1], za = ob[3 * ja + 2];
        const float xb = ob[3 * jb], yb = ob[3 * jb + 1], zb = ob[3 * jb + 2];
        ox2[p] = (v2f){-2.f * xa, -2.f * xb};
        oy2[p] = (v2f){-2.f * ya, -2.f * yb};
        oz2[p] = (v2f){-2.f * za, -2.f * zb};
        oq2[p] = (v2f){fmaf(xa, xa, fmaf(ya, ya, za * za)),
                       fmaf(xb, xb, fmaf(yb, yb, zb * zb))};
    }
    const float* hb = hand + (size_t)b * NH * 3;
    float* sw = &s_red[wave][0];
#pragma unroll 1
    for (int g = 0; g < FG; ++g) {
        float hx[FT], hy[FT], hz[FT], m[FT];
#pragma unroll
        for (int t = 0; t < FT; ++t) {
            const int h = min((bx * FG + g) * FT + t, NH - 1);
            hx[t] = hb[3 * h]; hy[t] = hb[3 * h + 1]; hz[t] = hb[3 * h + 2];
            m[t] = 3.4e38f;
        }
#pragma unroll
        for (int p = 0; p < FPP; ++p) {
#pragma unroll
            for (int t = 0; t < FT; ++t) {
                v2f a = __builtin_elementwise_fma(ox2[p], (v2f){hx[t], hx[t]}, oq2[p]);
                a = __builtin_elementwise_fma(oy2[p], (v2f){hy[t], hy[t]}, a);
                a = __builtin_elementwise_fma(oz2[p], (v2f){hz[t], hz[t]}, a);
                m[t] = fminf(fminf(a.x, a.y), m[t]);
            }
        }
#pragma unroll
        for (int t = 0; t < FT; ++t) {
            const float hq = fmaf(hx[t], hx[t], fmaf(hy[t], hy[t], hz[t] * hz[t]));
            sw[t * 65 + lane] = m[t] + hq;
        }
        __builtin_amdgcn_wave_barrier();
        float v = 3.4e38f;
        const int rb = r * 65 + seg * 16;
#pragma unroll
        for (int j = 0; j < 16; ++j) v = fminf(v, sw[rb + j]);
        __builtin_amdgcn_wave_barrier();
        v = fminf(v, __shfl_xor(v, 16));
        v = fminf(v, __shfl_xor(v, 32));
        if (seg == 0) {
            const int hidx = (bx * FG + g) * FT + r;
            if (hidx < NH) {
                const unsigned bits = __float_as_uint(fmaxf(v, 0.f));
                unsigned int* p = &minb[b * NH + hidx];
                if (bits < *((volatile unsigned int*)p)) atomicMin(p, bits);
            }
        }
    }
}

__global__ __launch_bounds__(256) void finalize_kernel(
    const float* __restrict__ dist, float* __restrict__ out, int B)
{
    constexpr float COLL = 0.005f;
    constexpr float CONT = 0.01f;
    const int total = B * NH;
    const int tid = threadIdx.x;
    double sum_d = 0.0, pen_sum = 0.0, att_sum = 0.0;
    int pen_cnt = 0, att_cnt = 0;
    for (int i = tid; i < total; i += 256) {
        const float d = sqrtf(fmaxf(dist[i], 0.f));
        sum_d += (double)d;
        if (d < COLL) { const float t = COLL - d; pen_sum += (double)(t * t); pen_cnt++; }
        const int n = i % NH;
        const bool isc = (n == 745) | (n == 317) | (n == 444) | (n == 556) |
                         (n == 673) | (n == 95)  | (n == 182) | (n == 234) |
                         (n == 279) | (n == 320);
        if (isc & (d > COLL) & (d < CONT)) { att_sum += (double)(d * d); att_cnt++; }
    }
    __shared__ double sd[256], sp[256], sa[256];
    __shared__ int    cp[256], ca[256];
    sd[tid] = sum_d; sp[tid] = pen_sum; sa[tid] = att_sum;
    cp[tid] = pen_cnt; ca[tid] = att_cnt;
    __syncthreads();
    for (int off = 128; off > 0; off >>= 1) {
        if (tid < off) {
            sd[tid] += sd[tid + off]; sp[tid] += sp[tid + off];
            sa[tid] += sa[tid + off];
            cp[tid] += cp[tid + off]; ca[tid] += ca[tid + off];
        }
        __syncthreads();
    }
    if (tid == 0) {
        const double pen_loss = cp[0] > 0 ? sp[0] / (double)cp[0] : 0.0;
        const double att_loss = ca[0] > 0 ? sa[0] / (double)ca[0] : 0.0;
        out[0] = (float)(100.0 * pen_loss + 10.0 * att_loss);
        out[1] = (float)pen_loss;
        out[2] = (float)att_loss;
        out[3] = (float)(sd[0] / (double)total);
        out[4] = (float)ca[0];
        out[5] = (float)cp[0];
    }
}

extern "C" void kernel_launch(void* const* d_in, const int* in_sizes, int n_in,
                              void* d_out, int out_size, void* d_ws, size_t ws_size,
                              hipStream_t stream) {
    const float* hand = (const float*)d_in[0];  // [B, 778, 3] fp32
    const float* obj  = (const float*)d_in[1];  // [B, V, 3]   fp32
    // d_in[2]/d_in[3] (faces): unused by the loss

    const int B = in_sizes[0] / (NH * 3);
    const int V = in_sizes[1] / (B * 3);
    const int total = B * V;
    const int nq = B * NH;

    // workspace layout: [0,64K) fallback dist | shards 4K | ocnt | cnt | buckets | ovf
    char* base = (char*)d_ws;
    size_t off = 65536;
    Shard* shards = (Shard*)(base + off);                         // 64*64B = 4KB
    int*   ocnt   = (int*)(base + off + 4096);                    // 1 int
    int*   cnt    = (int*)(base + off + 8192);                    // [B*NCELL]
    const size_t cnt_bytes = (size_t)B * NCELL * sizeof(int);
    const size_t boff = (off + 8192 + cnt_bytes + 255) & ~(size_t)255;
    float4* buckets = (float4*)(base + boff);                     // [B*NCELL*CAP]
    const size_t bkt_bytes = (size_t)B * NCELL * CAP * sizeof(float4);
    float4* ovf = (float4*)(base + boff + bkt_bytes);             // [B*V] worst case
    const size_t need = boff + bkt_bytes + (size_t)total * sizeof(float4);

    if (ws_size >= need) {
        // one-time sizing: co-residency-validated grid for the coop kernel
        static int s_nblk = 0;
        if (s_nblk == 0) {
            int dev = 0;
            (void)hipGetDevice(&dev);
            int coop = 0;
            (void)hipDeviceGetAttribute(&coop, hipDeviceAttributeCooperativeLaunch, dev);
            int perCU = 0;
            if (hipOccupancyMaxActiveBlocksPerMultiprocessor(
                    &perCU, mega_kernel, 256, 0) != hipSuccess || perCU <= 0)
                perCU = 2;
            int ncu = 0;
            if (hipDeviceGetAttribute(&ncu, hipDeviceAttributeMultiprocessorCount,
                                      dev) != hipSuccess || ncu <= 0)
                ncu = 256;
            s_nblk = coop ? perCU * ncu : -1;
        }

        int nblk = (s_nblk > 0) ? (s_nblk / B) * B : 0;   // multiple of B
        bool launched = false;
        if (nblk >= B) {
            float* outp = (float*)d_out;
            int Bv = B, Vv = V;
            void* kargs[] = {(void*)&hand, (void*)&obj, (void*)&cnt, (void*)&ocnt,
                             (void*)&buckets, (void*)&ovf, (void*)&shards,
                             (void*)&outp, (void*)&Bv, (void*)&Vv};
            hipError_t ce = hipLaunchCooperativeKernel(
                (const void*)mega_kernel, dim3(nblk), dim3(256), kargs, 0, stream);
            if (ce == hipSuccess) launched = true;
            else (void)hipGetLastError();   // clear, fall back
        }

        if (!launched) {
            // R14 multi-dispatch path
            (void)hipMemsetAsync(base + off, 0, 8192 + cnt_bytes, stream);
            const int bpb = (V + 1023) / 1024;
            int gbin = B * bpb; gbin = (gbin + NXCD - 1) & ~(NXCD - 1);
            bin_kernel<<<gbin, 256, 0, stream>>>(obj, cnt, ocnt, buckets, ovf,
                                                 B, V, bpb);
            const int bpq = (NH + 3) / 4;
            int gq = B * bpq; gq = (gq + NXCD - 1) & ~(NXCD - 1);
            query_kernel<<<gq, 256, 0, stream>>>(hand, cnt, buckets, ovf, ocnt,
                                                 shards, B, bpq);
            finalize_tiny<<<1, 64, 0, stream>>>(shards, (float*)d_out, nq);
        }
    } else {
        // brute-force fallback (uint bit-pattern mins == float d2)
        (void)hipMemsetAsync(d_ws, 0x7F, (size_t)nq * sizeof(unsigned int), stream);
        dim3 grid(FNBX, (V + FCHUNK - 1) / FCHUNK, B);
        nn_brute_kernel<<<grid, FBLK, 0, stream>>>(hand, obj,
                                                   (unsigned int*)d_ws, V);
        finalize_kernel<<<1, 256, 0, stream>>>((const float*)d_ws, (float*)d_out, B);
    }
}

// Round 6
// 89.223 us; speedup vs baseline: 3.5606x; 3.5606x over previous
//
#include <hip/hip_runtime.h>
#include <math.h>

// Problem constants
constexpr int NH    = 778;           // hand verts per batch
constexpr int GRIDC = 16;            // cells per axis (0.1 m cube -> 6.25 mm cells)
constexpr int NCELL = GRIDC * GRIDC * GRIDC;   // 4096
constexpr int CAP   = 40;            // bucket cap (Poisson mean ~9.8; P(>40)~1e-14)
constexpr float CELL     = 0.1f / GRIDC;       // 0.00625
constexpr float INV_CELL = GRIDC / 0.1f;       // 160
constexpr int NXCD = 8;              // MI355X XCD count
constexpr int NSH  = 64;             // stat shards, one 64B line each
constexpr int SPEC = 8;              // speculative bucket entries per lane (covers n<=16)

// R17 = R14 structure (multi-dispatch: memset -> bin -> query -> finalize_tiny)
// + ONE delta: speculative bucket reads in query (R15's idea, now isolated).
// R16 lesson: cooperative grid.sync() on MI355X costs ~100us/sync at 2048
// blocks (software barrier line bounced across 8 non-coherent XCDs; mega
// kernel ran 400us at VALUBusy 0.9%) — dispatch boundaries are CHEAPER.

struct alignas(64) Shard {
    double sd, sp, sa;   // sum_d, pen_sum, att_sum
    int cp, ca;          // pen_cnt, att_cnt
    int pad[3];
};

__device__ __forceinline__ int clampc(int v) {
    return min(GRIDC - 1, max(0, v));
}

// ---------------------------------------------------------------------------
// K1: bin obj points into per-(batch,cell) buckets. 4 points per thread via
// aligned float4 loads (R14: bin was dep-chain bound, not BW-bound).
// Overflow (idx >= CAP) -> global list tagged with batch (always exact).
// XCD-affinity remap: batch b served by XCD b (B==8).
// ---------------------------------------------------------------------------
__global__ __launch_bounds__(256) void bin_kernel(
    const float* __restrict__ obj,   // [B, V, 3] flat
    int* __restrict__ cnt,           // [B*NCELL]
    int* __restrict__ ocnt,          // overflow counter
    float4* __restrict__ buckets,    // [B*NCELL*CAP]
    float4* __restrict__ ovf,        // [B*V] worst case
    int B, int V, int bpb)           // bpb = blocks per batch (1024 pts/block)
{
    const int w = (blockIdx.x % NXCD) * (gridDim.x / NXCD) + blockIdx.x / NXCD;
    const int b = w / bpb;
    if (b >= B) return;
    const int p0 = ((w % bpb) * 256 + (int)threadIdx.x) * 4;
    if (p0 >= V) return;

    float px[4], py[4], pz[4];
    int np;
    const size_t fbase = ((size_t)b * V + p0) * 3;
    if (p0 + 4 <= V && (fbase & 3) == 0) {
        const float4* src = (const float4*)(obj + fbase);
        const float4 A = src[0], Bv = src[1], C = src[2];
        px[0]=A.x;  py[0]=A.y;  pz[0]=A.z;
        px[1]=A.w;  py[1]=Bv.x; pz[1]=Bv.y;
        px[2]=Bv.z; py[2]=Bv.w; pz[2]=C.x;
        px[3]=C.y;  py[3]=C.z;  pz[3]=C.w;
        np = 4;
    } else {
        np = min(4, V - p0);
        for (int q = 0; q < np; ++q) {
            px[q] = obj[fbase + 3 * q + 0];
            py[q] = obj[fbase + 3 * q + 1];
            pz[q] = obj[fbase + 3 * q + 2];
        }
    }

    const int cb = b * NCELL;
#pragma unroll
    for (int q = 0; q < 4; ++q) {
        if (q >= np) break;
        const int cx = clampc((int)(px[q] * INV_CELL));
        const int cy = clampc((int)(py[q] * INV_CELL));
        const int cz = clampc((int)(pz[q] * INV_CELL));
        const int cell = cb + (cz * GRIDC + cy) * GRIDC + cx;
        const int idx = atomicAdd(&cnt[cell], 1);
        if (idx < CAP) {
            buckets[(size_t)cell * CAP + idx] = make_float4(px[q], py[q], pz[q], 0.f);
        } else {
            const int oi = atomicAdd(ocnt, 1);   // oi < total always
            ovf[oi] = make_float4(px[q], py[q], pz[q], __int_as_float(b));
        }
    }
}

// ---------------------------------------------------------------------------
// K2: exact grid NN query — ONE WAVE PER QUERY — fused stats into padded
// shards (relaxed atomics; kernel-boundary visibility; no fence, no ticket).
// R17 delta: SPECULATIVE bucket loads — bp[sub+2j] addresses are independent
// of cnt, so 8 entries/lane issue in parallel WITH the cnt load: one L2
// round-trip per cell instead of 1 + n/2 dependent rounds (covers n<=16,
// ~98% of Poisson-9.8 cells; tail loop handles the rest; reads beyond n are
// stale-but-allocated bucket slots, masked out before use).
// Exactness: h lies inside its own cell, so after completing cube radius r-1
// every unscanned point is >= (r-1)*CELL away; stop iff best <= ((r-1)*CELL)^2.
// ---------------------------------------------------------------------------
__global__ __launch_bounds__(256) void query_kernel(
    const float* __restrict__ hand,    // [B, NH, 3] flat
    const int* __restrict__ cnt,       // [B*NCELL]
    const float4* __restrict__ buckets,// [B*NCELL*CAP]
    const float4* __restrict__ ovf,
    const int* __restrict__ ocnt,
    Shard* __restrict__ shards,        // [NSH]
    int B, int bpq)                    // bpq = blocks per batch (4 queries/block)
{
    constexpr float COLL = 0.005f;
    constexpr float CONT = 0.01f;
    const int tid  = threadIdx.x;
    const int wave = tid >> 6;
    const int lane = tid & 63;
    const int w  = (blockIdx.x % NXCD) * (gridDim.x / NXCD) + blockIdx.x / NXCD;
    const int b  = w / bpq;
    const int ql = (w % bpq) * 4 + wave;    // local query id in batch
    const bool valid = (b < B) && (ql < NH);

    float best = 3.4e38f;

    if (valid) {
        const int i = b * NH + ql;
        const float hx = hand[3 * i + 0];
        const float hy = hand[3 * i + 1];
        const float hz = hand[3 * i + 2];
        const int hcx = clampc((int)(hx * INV_CELL));
        const int hcy = clampc((int)(hy * INV_CELL));
        const int hcz = clampc((int)(hz * INV_CELL));
        const int cbase = b * NCELL;

        // phase 1: radius-1 cube (27 cells), 2 lanes per cell (lanes 0..53)
        if (lane < 54) {
            const int cl  = lane >> 1;
            const int sub = lane & 1;
            const int cx = hcx + (cl % 3) - 1;
            const int cy = hcy + ((cl / 3) % 3) - 1;
            const int cz = hcz + (cl / 9) - 1;
            if (cx >= 0 && cx < GRIDC && cy >= 0 && cy < GRIDC &&
                cz >= 0 && cz < GRIDC) {
                const int cell = cbase + (cz * GRIDC + cy) * GRIDC + cx;
                const float4* bp = buckets + (size_t)cell * CAP;
                const int n = min(cnt[cell], CAP);     // issues with loads below
                float4 e[SPEC];
#pragma unroll
                for (int j = 0; j < SPEC; ++j) e[j] = bp[sub + 2 * j];  // speculative
#pragma unroll
                for (int j = 0; j < SPEC; ++j) {
                    if (sub + 2 * j < n) {
                        const float dx = e[j].x - hx, dy = e[j].y - hy, dz = e[j].z - hz;
                        best = fminf(best, fmaf(dx, dx, fmaf(dy, dy, dz * dz)));
                    }
                }
                for (int k = sub + 2 * SPEC; k < n; k += 2) {   // rare tail (n>16)
                    const float4 p = bp[k];
                    const float dx = p.x - hx, dy = p.y - hy, dz = p.z - hz;
                    best = fminf(best, fmaf(dx, dx, fmaf(dy, dy, dz * dz)));
                }
            }
        }

        // overflow list (normally empty), lane-strided
        const int on = *ocnt;
        for (int k = lane; k < on; k += 64) {
            const float4 p = ovf[k];
            if (__float_as_int(p.w) == b) {
                const float dx = p.x - hx, dy = p.y - hy, dz = p.z - hz;
                best = fminf(best, fmaf(dx, dx, fmaf(dy, dy, dz * dz)));
            }
        }

#pragma unroll
        for (int d = 1; d < 64; d <<= 1) best = fminf(best, __shfl_xor(best, d));

        // rare path: expanding shells, lane-strided over shell cells
        for (int r = 2; r < GRIDC; ++r) {
            const float bnd = (float)(r - 1) * CELL;
            if (best <= bnd * bnd) break;
            const int side = 2 * r + 1;
            const int ncells = side * side * side;
            for (int ci = lane; ci < ncells; ci += 64) {
                const int dx = ci % side - r;
                const int dy = (ci / side) % side - r;
                const int dz = ci / (side * side) - r;
                if (max(max(abs(dx), abs(dy)), abs(dz)) != r) continue; // shell only
                const int cx = hcx + dx, cy = hcy + dy, cz = hcz + dz;
                if (cx < 0 || cx >= GRIDC || cy < 0 || cy >= GRIDC ||
                    cz < 0 || cz >= GRIDC) continue;
                const int cell = cbase + (cz * GRIDC + cy) * GRIDC + cx;
                const int n = min(cnt[cell], CAP);
                const float4* bp = buckets + (size_t)cell * CAP;
                for (int k = 0; k < n; ++k) {
                    const float4 p = bp[k];
                    const float ddx = p.x - hx, ddy = p.y - hy, ddz = p.z - hz;
                    best = fminf(best, fmaf(ddx, ddx, fmaf(ddy, ddy, ddz * ddz)));
                }
            }
#pragma unroll
            for (int d = 1; d < 64; d <<= 1) best = fminf(best, __shfl_xor(best, d));
        }
    }

    // ---- fused stats: per-block LDS reduction + 5 relaxed shard atomics ----
    __shared__ double ssd[4], ssp[4], ssa[4];
    __shared__ int scp[4], sca[4];
    if (lane == 0) {
        double sd = 0.0, sp = 0.0, sa = 0.0;
        int cp = 0, ca = 0;
        if (valid) {
            const float d = sqrtf(fmaxf(best, 0.f));
            sd = (double)d;
            if (d < COLL) { const float t = COLL - d; sp = (double)(t * t); cp = 1; }
            const bool isc = (ql == 745) | (ql == 317) | (ql == 444) | (ql == 556) |
                             (ql == 673) | (ql == 95)  | (ql == 182) | (ql == 234) |
                             (ql == 279) | (ql == 320);
            if (isc & (d > COLL) & (d < CONT)) { sa = (double)(d * d); ca = 1; }
        }
        ssd[wave] = sd; ssp[wave] = sp; ssa[wave] = sa;
        scp[wave] = cp; sca[wave] = ca;
    }
    __syncthreads();
    if (tid == 0) {
        Shard* s = &shards[blockIdx.x & (NSH - 1)];
        atomicAdd(&s->sd, ssd[0]+ssd[1]+ssd[2]+ssd[3]);
        atomicAdd(&s->sp, ssp[0]+ssp[1]+ssp[2]+ssp[3]);
        atomicAdd(&s->sa, ssa[0]+ssa[1]+ssa[2]+ssa[3]);
        atomicAdd(&s->cp, scp[0]+scp[1]+scp[2]+scp[3]);
        atomicAdd(&s->ca, sca[0]+sca[1]+sca[2]+sca[3]);
        // no fence, no ticket: next dispatch sees these (kernel boundary)
    }
}

// ---------------------------------------------------------------------------
// K3: 1-wave shard reduction -> 6 outputs
// ---------------------------------------------------------------------------
__global__ __launch_bounds__(64) void finalize_tiny(
    const Shard* __restrict__ shards, float* __restrict__ out, int nq)
{
    const int l = threadIdx.x;   // 64 threads, one shard each
    double sd = shards[l].sd, sp = shards[l].sp, sa = shards[l].sa;
    int cp = shards[l].cp, ca = shards[l].ca;
#pragma unroll
    for (int d = 1; d < 64; d <<= 1) {
        sd += __shfl_xor(sd, d);
        sp += __shfl_xor(sp, d);
        sa += __shfl_xor(sa, d);
        cp += __shfl_xor(cp, d);
        ca += __shfl_xor(ca, d);
    }
    if (l == 0) {
        const double pen_loss = cp > 0 ? sp / (double)cp : 0.0;
        const double att_loss = ca > 0 ? sa / (double)ca : 0.0;
        out[0] = (float)(100.0 * pen_loss + 10.0 * att_loss);
        out[1] = (float)pen_loss;
        out[2] = (float)att_loss;
        out[3] = (float)(sd / (double)nq);
        out[4] = (float)ca;
        out[5] = (float)cp;
    }
}

// ---------------------------------------------------------------------------
// Fallback brute-force (ws too small for grid). Unchanged from R10/R14.
// ---------------------------------------------------------------------------
typedef float v2f __attribute__((ext_vector_type(2)));
constexpr int FT = 16, FG = 4, FBLK = 256, FCHUNK = 2560;
constexpr int FNBX = (NH + FG * FT - 1) / (FG * FT);
constexpr int FLPP = FCHUNK / FBLK, FPP = FLPP / 2;

__global__ __launch_bounds__(FBLK, 2) void nn_brute_kernel(
    const float* __restrict__ hand, const float* __restrict__ obj,
    unsigned int* __restrict__ minb, int V)
{
    __shared__ float s_red[4][16 * 65];
    const int bx = blockIdx.x, c = blockIdx.y, b = blockIdx.z;
    const int tid = threadIdx.x, wave = tid >> 6, lane = tid & 63;
    const int r = lane & 15, seg = lane >> 4;
    const float* ob = obj + (size_t)b * V * 3;
    const int base = c * FCHUNK + tid;
    v2f ox2[FPP], oy2[FPP], oz2[FPP], oq2[FPP];
#pragma unroll
    for (int p = 0; p < FPP; ++p) {
        const int ja = min(base + (2 * p + 0) * FBLK, V - 1);
        const int jb = min(base + (2 * p + 1) * FBLK, V - 1);
        const float xa = ob[3 * ja], ya = ob[3 * ja + 1], za = ob[3 * ja + 2];
        const float xb = ob[3 * jb], yb = ob[3 * jb + 1], zb = ob[3 * jb + 2];
        ox2[p] = (v2f){-2.f * xa, -2.f * xb};
        oy2[p] = (v2f){-2.f * ya, -2.f * yb};
        oz2[p] = (v2f){-2.f * za, -2.f * zb};
        oq2[p] = (v2f){fmaf(xa, xa, fmaf(ya, ya, za * za)),
                       fmaf(xb, xb, fmaf(yb, yb, zb * zb))};
    }
    const float* hb = hand + (size_t)b * NH * 3;
    float* sw = &s_red[wave][0];
#pragma unroll 1
    for (int g = 0; g < FG; ++g) {
        float hx[FT], hy[FT], hz[FT], m[FT];
#pragma unroll
        for (int t = 0; t < FT; ++t) {
            const int h = min((bx * FG + g) * FT + t, NH - 1);
            hx[t] = hb[3 * h]; hy[t] = hb[3 * h + 1]; hz[t] = hb[3 * h + 2];
            m[t] = 3.4e38f;
        }
#pragma unroll
        for (int p = 0; p < FPP; ++p) {
#pragma unroll
            for (int t = 0; t < FT; ++t) {
                v2f a = __builtin_elementwise_fma(ox2[p], (v2f){hx[t], hx[t]}, oq2[p]);
                a = __builtin_elementwise_fma(oy2[p], (v2f){hy[t], hy[t]}, a);
                a = __builtin_elementwise_fma(oz2[p], (v2f){hz[t], hz[t]}, a);
                m[t] = fminf(fminf(a.x, a.y), m[t]);
            }
        }
#pragma unroll
        for (int t = 0; t < FT; ++t) {
            const float hq = fmaf(hx[t], hx[t], fmaf(hy[t], hy[t], hz[t] * hz[t]));
            sw[t * 65 + lane] = m[t] + hq;
        }
        __builtin_amdgcn_wave_barrier();
        float v = 3.4e38f;
        const int rb = r * 65 + seg * 16;
#pragma unroll
        for (int j = 0; j < 16; ++j) v = fminf(v, sw[rb + j]);
        __builtin_amdgcn_wave_barrier();
        v = fminf(v, __shfl_xor(v, 16));
        v = fminf(v, __shfl_xor(v, 32));
        if (seg == 0) {
            const int hidx = (bx * FG + g) * FT + r;
            if (hidx < NH) {
                const unsigned bits = __float_as_uint(fmaxf(v, 0.f));
                unsigned int* p = &minb[b * NH + hidx];
                if (bits < *((volatile unsigned int*)p)) atomicMin(p, bits);
            }
        }
    }
}

__global__ __launch_bounds__(256) void finalize_kernel(
    const float* __restrict__ dist, float* __restrict__ out, int B)
{
    constexpr float COLL = 0.005f;
    constexpr float CONT = 0.01f;
    const int total = B * NH;
    const int tid = threadIdx.x;
    double sum_d = 0.0, pen_sum = 0.0, att_sum = 0.0;
    int pen_cnt = 0, att_cnt = 0;
    for (int i = tid; i < total; i += 256) {
        const float d = sqrtf(fmaxf(dist[i], 0.f));
        sum_d += (double)d;
        if (d < COLL) { const float t = COLL - d; pen_sum += (double)(t * t); pen_cnt++; }
        const int n = i % NH;
        const bool isc = (n == 745) | (n == 317) | (n == 444) | (n == 556) |
                         (n == 673) | (n == 95)  | (n == 182) | (n == 234) |
                         (n == 279) | (n == 320);
        if (isc & (d > COLL) & (d < CONT)) { att_sum += (double)(d * d); att_cnt++; }
    }
    __shared__ double sd[256], sp[256], sa[256];
    __shared__ int    cp[256], ca[256];
    sd[tid] = sum_d; sp[tid] = pen_sum; sa[tid] = att_sum;
    cp[tid] = pen_cnt; ca[tid] = att_cnt;
    __syncthreads();
    for (int off = 128; off > 0; off >>= 1) {
        if (tid < off) {
            sd[tid] += sd[tid + off]; sp[tid] += sp[tid + off];
            sa[tid] += sa[tid + off];
            cp[tid] += cp[tid + off]; ca[tid] += ca[tid + off];
        }
        __syncthreads();
    }
    if (tid == 0) {
        const double pen_loss = cp[0] > 0 ? sp[0] / (double)cp[0] : 0.0;
        const double att_loss = ca[0] > 0 ? sa[0] / (double)ca[0] : 0.0;
        out[0] = (float)(100.0 * pen_loss + 10.0 * att_loss);
        out[1] = (float)pen_loss;
        out[2] = (float)att_loss;
        out[3] = (float)(sd[0] / (double)total);
        out[4] = (float)ca[0];
        out[5] = (float)cp[0];
    }
}

extern "C" void kernel_launch(void* const* d_in, const int* in_sizes, int n_in,
                              void* d_out, int out_size, void* d_ws, size_t ws_size,
                              hipStream_t stream) {
    const float* hand = (const float*)d_in[0];  // [B, 778, 3] fp32
    const float* obj  = (const float*)d_in[1];  // [B, V, 3]   fp32
    // d_in[2]/d_in[3] (faces): unused by the loss

    const int B = in_sizes[0] / (NH * 3);
    const int V = in_sizes[1] / (B * 3);
    const int total = B * V;
    const int nq = B * NH;

    // workspace layout: [0,64K) fallback dist | shards 4K | ocnt | cnt | buckets | ovf
    char* base = (char*)d_ws;
    size_t off = 65536;
    Shard* shards = (Shard*)(base + off);                         // 64*64B = 4KB
    int*   ocnt   = (int*)(base + off + 4096);                    // 1 int
    int*   cnt    = (int*)(base + off + 8192);                    // [B*NCELL]
    const size_t cnt_bytes = (size_t)B * NCELL * sizeof(int);
    const size_t boff = (off + 8192 + cnt_bytes + 255) & ~(size_t)255;
    float4* buckets = (float4*)(base + boff);                     // [B*NCELL*CAP]
    const size_t bkt_bytes = (size_t)B * NCELL * CAP * sizeof(float4);
    float4* ovf = (float4*)(base + boff + bkt_bytes);             // [B*V] worst case
    const size_t need = boff + bkt_bytes + (size_t)total * sizeof(float4);

    if (ws_size >= need) {
        // one fill zeroes shards + ocnt + cell counts (~136 KB)
        (void)hipMemsetAsync(base + off, 0, 8192 + cnt_bytes, stream);

        // bin: 4 points/thread, 1024 points/block, XCD-affinity remap
        const int bpb = (V + 1023) / 1024;
        int gbin = B * bpb; gbin = (gbin + NXCD - 1) & ~(NXCD - 1);
        bin_kernel<<<gbin, 256, 0, stream>>>(obj, cnt, ocnt, buckets, ovf,
                                             B, V, bpb);

        // query: 1 wave/query, 4 queries/block, same batch->XCD mapping,
        // stats fused into padded shards
        const int bpq = (NH + 3) / 4;   // 195
        int gq = B * bpq; gq = (gq + NXCD - 1) & ~(NXCD - 1);
        query_kernel<<<gq, 256, 0, stream>>>(hand, cnt, buckets, ovf, ocnt,
                                             shards, B, bpq);

        finalize_tiny<<<1, 64, 0, stream>>>(shards, (float*)d_out, nq);
    } else {
        // brute-force fallback (uint bit-pattern mins == float d2)
        (void)hipMemsetAsync(d_ws, 0x7F, (size_t)nq * sizeof(unsigned int), stream);
        dim3 grid(FNBX, (V + FCHUNK - 1) / FCHUNK, B);
        nn_brute_kernel<<<grid, FBLK, 0, stream>>>(hand, obj,
                                                   (unsigned int*)d_ws, V);
        finalize_kernel<<<1, 256, 0, stream>>>((const float*)d_ws, (float*)d_out, B);
    }
}